// Round 3
// baseline (171.509 us; speedup 1.0000x reference)
//
#include <hip/hip_runtime.h>

// SRL embeddings — R5: two-kernel split (prologue scan + streaming main).
// Shapes fixed: B=16,S=16,L=128,D=768,A=8,T=5.
//
// R3/R4 post-mortem: Phase B (sid scan + select + list build) was recomputed
// by every chunk-block (6-12x redundant) and barrier-coupled into every
// block's streaming phase; adding blocks/waves for tail smoothing multiplied
// that cost, which is why both occupancy attempts regressed.
//
// R5: hoist Phase B into srl_prep (256 blocks x 128 thr, ~2us): writes
// len[bs], scnt[bs][24], slist[bs][24][128] into d_ws. Main kernel becomes
// pure streaming: no sid staging, no serial wave-0 work, single barrier for
// the pooling reduction. That makes CHUNK=16 (3072 blocks, ~8 resident/CU,
// 12/CU offered -> ~4/CU dynamic) safe for smoothing the len tail.

namespace {
constexpr int Bc = 16, Sc = 16, Lc = 128, Dc = 768, Ac = 8, Tc = 5;
constexpr int NF4    = Dc / 4;          // 192 float4 per row
constexpr int CHUNK  = 16;              // float4 columns per block (256B slice)
constexpr int NCHUNK = NF4 / CHUNK;     // 12
constexpr int BLOCK  = 256;             // 4 waves
constexpr int RP     = BLOCK / CHUNK;   // 16 l-phases
constexpr int NSLOT  = 3 * Ac;          // 24 arg slots
constexpr int OUT1   = Bc * Sc * NF4;       // sentence output, float4 units
constexpr int OUTG   = Bc * Sc * Ac * NF4;  // per-arg-type output, float4 units
constexpr int NBS    = Bc * Sc;         // 256 sentences
}

// ---------------------------------------------------------------------------
// Prologue: per-(b,s) sentence scan. One block per (b,s), 128 threads.
// Writes: wlen[bs], wscnt[bs*24+j], wslist[(bs*24+j)*128 + i] (row indices).
// ---------------------------------------------------------------------------
__global__ __launch_bounds__(Lc) void srl_prep(
    const int* __restrict__ sids,
    const int* __restrict__ amask,
    const int* __restrict__ pids,
    const int* __restrict__ a0ids,
    const int* __restrict__ a1ids,
    int*           __restrict__ wlen,
    int*           __restrict__ wscnt,
    unsigned char* __restrict__ wslist)
{
  const int bs  = blockIdx.x;
  const int tid = threadIdx.x;

  __shared__ int sid[Lc];
  __shared__ int seltok[NSLOT];   // -1 if no valid token
  __shared__ int cur[NSLOT];      // append cursors

  sid[tid] = sids[bs * Lc + tid];
  const int mval = amask[bs * Lc + tid];
  const int len  = __syncthreads_count(mval != 0);   // barrier: sid published
  if (tid == 0) wlen[bs] = len;

  // 24 lanes: count matches for all 5 tokens in one sid pass, pick LAST
  // valid token (tok!=0 && cnt>0).
  if (tid < NSLOT) {
    const int g = tid / Ac, a = tid % Ac;
    const int* ids = (g == 0 ? pids : (g == 1 ? a0ids : a1ids)) + (bs * Ac + a) * Tc;
    int tok[Tc], cnt[Tc];
#pragma unroll
    for (int t = 0; t < Tc; ++t) { tok[t] = ids[t]; cnt[t] = 0; }
    for (int l = 0; l < Lc; ++l) {
      const int v = sid[l];   // broadcast read
#pragma unroll
      for (int t = 0; t < Tc; ++t) cnt[t] += (v == tok[t]) ? 1 : 0;
    }
    int sel = -1, n = 0;
#pragma unroll
    for (int t = Tc - 1; t >= 0; --t) {
      if (n == 0 && tok[t] != 0 && cnt[t] > 0) { sel = tok[t]; n = cnt[t]; }
    }
    wscnt[bs * NSLOT + tid] = n;
    seltok[tid] = (n > 0) ? sel : -1;   // -1 cannot match any sid
    cur[tid]    = 0;
  }
  __syncthreads();   // seltok/cur ready

  // List build: 128 threads, one per row; order irrelevant (mean follows).
  const int v = sid[tid];
#pragma unroll
  for (int j = 0; j < NSLOT; ++j) {
    if (v == seltok[j]) {
      const int p = atomicAdd(&cur[j], 1);
      wslist[(bs * NSLOT + j) * Lc + p] = (unsigned char)tid;
    }
  }
}

// ---------------------------------------------------------------------------
// Main: pure streaming. Grid (12 chunks, 256 bs) x 256 threads.
// ---------------------------------------------------------------------------
__global__ __launch_bounds__(BLOCK) void srl_main(
    const float4* __restrict__ hid,
    const int*           __restrict__ wlen,
    const int*           __restrict__ wscnt,
    const unsigned char* __restrict__ wslist,
    float4*       __restrict__ out)
{
  const int c   = blockIdx.x;           // column chunk 0..11
  const int bs  = blockIdx.y;           // (b,s) 0..255
  const int tid = threadIdx.x;
  const int q   = tid & (CHUNK - 1);    // float4 column within chunk
  const int r   = tid >> 4;             // l-phase 0..15

  __shared__ float4 red[BLOCK];

  const int len = wlen[bs];             // uniform scalar load
  const float4* __restrict__ hrow = hid + (size_t)bs * Lc * NF4 + c * CHUNK;

  // Pooling partial sums over the valid prefix, l-split by r.
  float ax = 0.f, ay = 0.f, az = 0.f, aw = 0.f;
#pragma unroll 2
  for (int l = r; l < len; l += RP) {
    const float4 v = hrow[l * NF4 + q];
    ax += v.x; ay += v.y; az += v.z; aw += v.w;
  }
  red[tid] = make_float4(ax, ay, az, aw);
  __syncthreads();

  // Reduce the 16 l-phases, divide by len, write sentence embedding.
  if (tid < CHUNK) {
    float4 s = red[tid];
#pragma unroll
    for (int p = 1; p < RP; ++p) {
      const float4 t = red[p * CHUNK + tid];
      s.x += t.x; s.y += t.y; s.z += t.z; s.w += t.w;
    }
    const float inv = 1.0f / (float)(len > 0 ? len : 1);
    s.x *= inv; s.y *= inv; s.z *= inv; s.w *= inv;
    out[bs * NF4 + c * CHUNK + tid] = s;
  }

  // Arg embeddings: r=0..7 handle slots {r, r+16}, r=8..15 handle slot r.
  // Match rows are L2-hot (streamed moments ago by this block).
  for (int j = r; j < NSLOT; j += RP) {
    const int n = wscnt[bs * NSLOT + j];
    float ox = 0.f, oy = 0.f, oz = 0.f, ow = 0.f;
    if (n > 0) {
      const unsigned char* lst = wslist + (bs * NSLOT + j) * Lc;
      for (int i = 0; i < n; ++i) {
        const int l = (int)lst[i];      // same addr across 16-lane group
        const float4 v = hrow[l * NF4 + q];
        ox += v.x; oy += v.y; oz += v.z; ow += v.w;
      }
      const float inv = 1.0f / (float)n;
      ox *= inv; oy *= inv; oz *= inv; ow *= inv;
    }
    const int g = j / Ac, a = j - g * Ac;
    out[OUT1 + g * OUTG + (bs * Ac + a) * NF4 + c * CHUNK + q] =
        make_float4(ox, oy, oz, ow);
  }
}

extern "C" void kernel_launch(void* const* d_in, const int* in_sizes, int n_in,
                              void* d_out, int out_size, void* d_ws, size_t ws_size,
                              hipStream_t stream) {
  const float4* hid   = (const float4*)d_in[0];
  const int*    sids  = (const int*)d_in[1];
  const int*    amask = (const int*)d_in[2];
  const int*    pids  = (const int*)d_in[3];
  const int*    a0ids = (const int*)d_in[4];
  const int*    a1ids = (const int*)d_in[5];
  float4*       out   = (float4*)d_out;

  // Workspace layout: len[256] | scnt[256*24] | slist[256*24*128] (uchar)
  int*           wlen   = (int*)d_ws;
  int*           wscnt  = wlen + NBS;
  unsigned char* wslist = (unsigned char*)(wscnt + NBS * NSLOT);

  srl_prep<<<dim3(NBS), dim3(Lc), 0, stream>>>(
      sids, amask, pids, a0ids, a1ids, wlen, wscnt, wslist);
  srl_main<<<dim3(NCHUNK, NBS), dim3(BLOCK), 0, stream>>>(
      hid, wlen, wscnt, wslist, out);
}